// Round 5
// baseline (162.031 us; speedup 1.0000x reference)
//
#include <hip/hip_runtime.h>
#include <math.h>

#define NN 512
#define BB 16
#define TOTAL (BB * NN * NN)   // 4,194,304 cells
#define EPS_F 1e-5f
#define DELTA_F 0.05f

#define HALO 16
#define LR   96                 // 64 + 2*HALO register tile
#define TTI  10                 // Jacobi iterations per launch (5 launches = 50)

// lane gets lane-1 (within each 16-lane DPP row); boundary lanes -> 0
__device__ __forceinline__ float dpp_shr1(float x) {
    int r = __builtin_amdgcn_update_dpp(0, __float_as_int(x), 0x111, 0xf, 0xf, true);
    return __int_as_float(r);
}
// lane gets lane+1; boundary lanes -> 0
__device__ __forceinline__ float dpp_shl1(float x) {
    int r = __builtin_amdgcn_update_dpp(0, __float_as_int(x), 0x101, 0xf, 0xf, true);
    return __int_as_float(r);
}

// ---------------------------------------------------------------------------
// Init: u0 = dir ? bc : 0 ; cmask = fluid(1)/dirichlet(0)
// ---------------------------------------------------------------------------
__global__ __launch_bounds__(256) void init_kernel(
    const float* __restrict__ x_mix,
    float* __restrict__ u,
    unsigned char* __restrict__ cmask)
{
    int idx = blockIdx.x * blockDim.x + threadIdx.x;
    if (idx >= TOTAL) return;
    int j = idx & (NN - 1);
    int i = (idx >> 9) & (NN - 1);
    float4 xm = reinterpret_cast<const float4*>(x_mix)[idx];
    bool edge = (i == 0) | (i == NN - 1) | (j == 0) | (j == NN - 1);
    bool dir  = edge || (xm.z > 0.5f);
    cmask[idx] = dir ? 0 : 1;
    u[idx]     = dir ? xm.w : 0.0f;
}

// ---------------------------------------------------------------------------
// Register-tile temporal-blocked stencil.
// 16x16 threads, each owns a 6x6 block of a 96x96 tile (64x64 output,
// halo 16 >= TTI). u AND the fluid coefficients live in VGPRs (pinned via
// opaque asm so the compiler cannot sink the mask loads back into the loop);
// vertical halo via transposed conflict-free LDS (double-buffered, 1
// barrier/iter); horizontal halo via DPP lane shifts. Ring cells frozen
// (cf=0) annihilate garbage halo values through fma(cf, ., old).
// ---------------------------------------------------------------------------
template<bool FINAL>
__global__ __launch_bounds__(256, 2) void stencil_kernel(
    const float* __restrict__ uin,
    float* __restrict__ uout,
    const unsigned char* __restrict__ cmask,
    const float* __restrict__ x_mix,
    const float* __restrict__ w_back,
    const float* __restrict__ b_back,
    const float* __restrict__ logit,
    const float* __restrict__ y_mean,
    const float* __restrict__ y_std)
{
    __shared__ float xup[2][6][256];   // each thread's row 0 (consumed by tr-1)
    __shared__ float xdn[2][6][256];   // each thread's row 5 (consumed by tr+1)

    const int b   = blockIdx.z;
    const int oy  = blockIdx.y * 64;
    const int ox  = blockIdx.x * 64;
    const int tid = threadIdx.x;
    const int tr  = tid >> 4;
    const int tc  = tid & 15;
    const int R0  = tr * 6;
    const int C0  = tc * 6;

    const float* ub = uin + (size_t)b * NN * NN;
    const unsigned char* cb = cmask + (size_t)b * NN * NN;

    float u[6][6];
    float cf[6][6];   // 1.0 = fluid (update), 0.0 = Dirichlet/frozen

    // ---- setup: load 6x6 u + coeffs (clamped; tile ring frozen) ----
#pragma unroll
    for (int r = 0; r < 6; ++r) {
        int ty = R0 + r;
        int gi = oy - HALO + ty;
        gi = min(max(gi, 0), NN - 1);
#pragma unroll
        for (int c = 0; c < 6; ++c) {
            int tx = C0 + c;
            int gj = ox - HALO + tx;
            gj = min(max(gj, 0), NN - 1);
            u[r][c] = ub[gi * NN + gj];
            unsigned m = cb[gi * NN + gj];
            bool ring = (ty == 0) | (ty == LR - 1) | (tx == 0) | (tx == LR - 1);
            cf[r][c] = (ring || m == 0u) ? 0.0f : 1.0f;
        }
    }

    // Pin u and cf into VGPRs: opaque defs stop the compiler from sinking
    // the global loads (esp. the cmask byte loads) into the iteration loop.
#pragma unroll
    for (int r = 0; r < 6; ++r)
#pragma unroll
        for (int c = 0; c < 6; ++c)
            asm volatile("" : "+v"(u[r][c]), "+v"(cf[r][c]));

    const int tup = (tid >= 16)  ? tid - 16 : tid;   // clamped neighbor indices
    const int tdn = (tid < 240)  ? tid + 16 : tid;

    // ---- TTI fused Jacobi iterations, all in registers ----
#pragma unroll 1
    for (int t = 0; t < TTI; ++t) {
        const int pb = t & 1;
        // publish OLD boundary rows (transposed layout: conflict-free b32)
#pragma unroll
        for (int w = 0; w < 6; ++w) {
            xup[pb][w][tid] = u[0][w];
            xdn[pb][w][tid] = u[5][w];
        }
        // capture OLD horizontal neighbor cols via DPP (pure VALU)
        float lsh[6], rsh[6];
#pragma unroll
        for (int r = 0; r < 6; ++r) {
            lsh[r] = dpp_shr1(u[r][5]);
            rsh[r] = dpp_shl1(u[r][0]);
        }
        __syncthreads();
        float th[6], bh[6];
#pragma unroll
        for (int w = 0; w < 6; ++w) {
            th[w] = xdn[pb][w][tup];   // garbage for tr==0: ring cf=0 kills it
            bh[w] = xup[pb][w][tdn];   // garbage for tr==15: ring cf=0 kills it
        }
        // in-register raster update; orow/prow keep OLD values (pure SSA)
        float prow[6];
#pragma unroll
        for (int c = 0; c < 6; ++c) prow[c] = th[c];
#pragma unroll
        for (int r = 0; r < 6; ++r) {
            float orow[6];
#pragma unroll
            for (int c = 0; c < 6; ++c) orow[c] = u[r][c];
#pragma unroll
            for (int c = 0; c < 6; ++c) {
                float up = prow[c];
                float dn = (r < 5) ? u[r + 1][c] : bh[c];
                float lf = (c > 0) ? orow[c - 1] : lsh[r];
                float rt = (c < 5) ? orow[c + 1] : rsh[r];
                float s  = (up + dn) + (lf + rt);
                float od = orow[c];
                float tq = __builtin_fmaf(0.25f, s, -od);
                u[r][c]  = __builtin_fmaf(cf[r][c], tq, od);
            }
#pragma unroll
            for (int c = 0; c < 6; ++c) prow[c] = orow[c];
        }
    }

    // ---- store center 64x64 (optionally fused epilogue) ----
    float* og = uout + (size_t)b * NN * NN;
    if (!FINAL) {
#pragma unroll
        for (int r = 0; r < 6; ++r) {
            int ty = R0 + r - HALO;
#pragma unroll
            for (int c = 0; c < 6; ++c) {
                int tx = C0 + c - HALO;
                if ((unsigned)ty < 64u && (unsigned)tx < 64u)
                    og[(size_t)(oy + ty) * NN + (ox + tx)] = u[r][c];
            }
        }
    } else {
        float w0  = w_back[0], w1 = w_back[1], bb0 = b_back[0];
        float rs  = 0.25f / (1.0f + expf(-logit[0]));
        float ym  = y_mean[0];
        float ysd = y_std[0] + EPS_F;
        const float4* xm4 = (const float4*)x_mix;
#pragma unroll
        for (int r = 0; r < 6; ++r) {
            int ty = R0 + r - HALO;
#pragma unroll
            for (int c = 0; c < 6; ++c) {
                int tx = C0 + c - HALO;
                if ((unsigned)ty < 64u && (unsigned)tx < 64u) {
                    int gi = oy + ty, gj = ox + tx;
                    size_t gidx = (size_t)b * NN * NN + (size_t)gi * NN + gj;
                    float4 xm = xm4[gidx];
                    float e  = (u[r][c] - ym) / ysd;
                    float rr = xm.x * w0 + xm.y * w1 + bb0;
                    float xs = (float)gi * (1.0f / 511.0f);
                    float ys = (float)gj * (1.0f / 511.0f);
                    float dd = fminf(fminf(xs, 1.0f - xs), fminf(ys, 1.0f - ys));
                    float ww = fminf(fmaxf(dd * (1.0f / DELTA_F), 0.0f), 1.0f);
                    if (xm.z > 0.5f) ww = 0.0f;
                    og[(size_t)gi * NN + gj] = e + ww * rs * rr;
                }
            }
        }
    }
}

// ---------------------------------------------------------------------------
extern "C" void kernel_launch(void* const* d_in, const int* in_sizes, int n_in,
                              void* d_out, int out_size, void* d_ws, size_t ws_size,
                              hipStream_t stream)
{
    const float* x_mix  = (const float*)d_in[0];
    const float* w_back = (const float*)d_in[1];
    const float* b_back = (const float*)d_in[2];
    const float* logit  = (const float*)d_in[3];
    const float* y_mean = (const float*)d_in[4];
    const float* y_std  = (const float*)d_in[5];

    float* out = (float*)d_out;

    // Workspace: u_a (16 MB floats) | cmask (4 MB bytes)
    float* u_a = (float*)d_ws;
    unsigned char* cmask = (unsigned char*)((char*)d_ws + (size_t)TOTAL * sizeof(float));

    const int block = 256;
    const int grid1d = (TOTAL + block - 1) / block;

    init_kernel<<<grid1d, block, 0, stream>>>(x_mix, u_a, cmask);

    // 50 iters = 5 launches x TTI(=10). Chain: a->out->a->out->a->(FINAL)->out
    dim3 sgrid(NN / 64, NN / 64, BB);   // 8 x 8 x 16 = 1024 blocks (4/CU)
    stencil_kernel<false><<<sgrid, block, 0, stream>>>(u_a, out, cmask, x_mix,
        w_back, b_back, logit, y_mean, y_std);
    stencil_kernel<false><<<sgrid, block, 0, stream>>>(out, u_a, cmask, x_mix,
        w_back, b_back, logit, y_mean, y_std);
    stencil_kernel<false><<<sgrid, block, 0, stream>>>(u_a, out, cmask, x_mix,
        w_back, b_back, logit, y_mean, y_std);
    stencil_kernel<false><<<sgrid, block, 0, stream>>>(out, u_a, cmask, x_mix,
        w_back, b_back, logit, y_mean, y_std);
    stencil_kernel<true><<<sgrid, block, 0, stream>>>(u_a, out, cmask, x_mix,
        w_back, b_back, logit, y_mean, y_std);
}

// Round 6
// 155.613 us; speedup vs baseline: 1.0412x; 1.0412x over previous
//
#include <hip/hip_runtime.h>
#include <math.h>

#define NN 512
#define BB 16
#define TOTAL (BB * NN * NN)   // 4,194,304 cells
#define EPS_F 1e-5f
#define DELTA_F 0.05f

#define HALO 8
#define LR   80                 // 64 + 2*HALO register tile
#define PT   5                  // cells per thread per dim (80/16)

// lane gets lane-1 (within each 16-lane DPP row); boundary lanes -> 0
__device__ __forceinline__ float dpp_shr1(float x) {
    int r = __builtin_amdgcn_update_dpp(0, __float_as_int(x), 0x111, 0xf, 0xf, true);
    return __int_as_float(r);
}
// lane gets lane+1; boundary lanes -> 0
__device__ __forceinline__ float dpp_shl1(float x) {
    int r = __builtin_amdgcn_update_dpp(0, __float_as_int(x), 0x101, 0xf, 0xf, true);
    return __int_as_float(r);
}

// ---------------------------------------------------------------------------
// Init: u0 = dir ? bc : 0 ; cmask = fluid(1)/dirichlet(0)
// ---------------------------------------------------------------------------
__global__ __launch_bounds__(256) void init_kernel(
    const float* __restrict__ x_mix,
    float* __restrict__ u,
    unsigned char* __restrict__ cmask)
{
    int idx = blockIdx.x * blockDim.x + threadIdx.x;
    if (idx >= TOTAL) return;
    int j = idx & (NN - 1);
    int i = (idx >> 9) & (NN - 1);
    float4 xm = reinterpret_cast<const float4*>(x_mix)[idx];
    bool edge = (i == 0) | (i == NN - 1) | (j == 0) | (j == NN - 1);
    bool dir  = edge || (xm.z > 0.5f);
    cmask[idx] = dir ? 0 : 1;
    u[idx]     = dir ? xm.w : 0.0f;
}

// ---------------------------------------------------------------------------
// Register-tile temporal-blocked stencil, 5x5 cells/thread.
// 16x16 threads own an 80x80 tile (64x64 output, halo 8 >= ITERS).
// u and fluid coeffs in VGPRs (honest fit under the 128-reg cap -> no
// AGPR-spill movs). Vertical halo via transposed conflict-free LDS
// (double-buffered, 1 barrier/iter); horizontal halo via DPP lane shifts.
// Ring cells frozen (cf=0) annihilate garbage halo values via fma.
// ---------------------------------------------------------------------------
template<int ITERS, bool FINAL>
__global__ __launch_bounds__(256, 4) void stencil_kernel(
    const float* __restrict__ uin,
    float* __restrict__ uout,
    const unsigned char* __restrict__ cmask,
    const float* __restrict__ x_mix,
    const float* __restrict__ w_back,
    const float* __restrict__ b_back,
    const float* __restrict__ logit,
    const float* __restrict__ y_mean,
    const float* __restrict__ y_std)
{
    __shared__ float xup[2][PT][256];   // thread's row 0 (consumed by tr-1)
    __shared__ float xdn[2][PT][256];   // thread's row PT-1 (consumed by tr+1)

    const int b   = blockIdx.z;
    const int oy  = blockIdx.y * 64;
    const int ox  = blockIdx.x * 64;
    const int tid = threadIdx.x;
    const int tr  = tid >> 4;
    const int tc  = tid & 15;
    const int R0  = tr * PT;
    const int C0  = tc * PT;

    const float* ub = uin + (size_t)b * NN * NN;
    const unsigned char* cb = cmask + (size_t)b * NN * NN;

    float u[PT][PT];
    float cf[PT][PT];   // 1.0 = fluid (update), 0.0 = Dirichlet/frozen

    // ---- setup: load 5x5 u + coeffs (clamped; tile ring frozen) ----
#pragma unroll
    for (int r = 0; r < PT; ++r) {
        int ty = R0 + r;
        int gi = oy - HALO + ty;
        gi = min(max(gi, 0), NN - 1);
#pragma unroll
        for (int c = 0; c < PT; ++c) {
            int tx = C0 + c;
            int gj = ox - HALO + tx;
            gj = min(max(gj, 0), NN - 1);
            u[r][c] = ub[gi * NN + gj];
            unsigned m = cb[gi * NN + gj];
            bool ring = (ty == 0) | (ty == LR - 1) | (tx == 0) | (tx == LR - 1);
            cf[r][c] = (ring || m == 0u) ? 0.0f : 1.0f;
        }
    }

    const int tup = (tid >= 16)  ? tid - 16 : tid;   // clamped neighbor indices
    const int tdn = (tid < 240)  ? tid + 16 : tid;

    // ---- ITERS fused Jacobi iterations, all in registers ----
#pragma unroll 1
    for (int t = 0; t < ITERS; ++t) {
        const int pb = t & 1;
        // publish OLD boundary rows (transposed layout: conflict-free b32)
#pragma unroll
        for (int w = 0; w < PT; ++w) {
            xup[pb][w][tid] = u[0][w];
            xdn[pb][w][tid] = u[PT - 1][w];
        }
        // capture OLD horizontal neighbor cols via DPP (pure VALU)
        float lsh[PT], rsh[PT];
#pragma unroll
        for (int r = 0; r < PT; ++r) {
            lsh[r] = dpp_shr1(u[r][PT - 1]);
            rsh[r] = dpp_shl1(u[r][0]);
        }
        __syncthreads();
        float th[PT], bh[PT];
#pragma unroll
        for (int w = 0; w < PT; ++w) {
            th[w] = xdn[pb][w][tup];   // garbage for tr==0: ring cf=0 kills it
            bh[w] = xup[pb][w][tdn];   // garbage for tr==15: ring cf=0 kills it
        }
        // in-register raster update; orow/prow keep OLD values (pure SSA)
        float prow[PT];
#pragma unroll
        for (int c = 0; c < PT; ++c) prow[c] = th[c];
#pragma unroll
        for (int r = 0; r < PT; ++r) {
            float orow[PT];
#pragma unroll
            for (int c = 0; c < PT; ++c) orow[c] = u[r][c];
#pragma unroll
            for (int c = 0; c < PT; ++c) {
                float up = prow[c];
                float dn = (r < PT - 1) ? u[r + 1][c] : bh[c];
                float lf = (c > 0)      ? orow[c - 1] : lsh[r];
                float rt = (c < PT - 1) ? orow[c + 1] : rsh[r];
                float s  = (up + dn) + (lf + rt);
                float od = orow[c];
                float tq = __builtin_fmaf(0.25f, s, -od);
                u[r][c]  = __builtin_fmaf(cf[r][c], tq, od);
            }
#pragma unroll
            for (int c = 0; c < PT; ++c) prow[c] = orow[c];
        }
    }

    // ---- store center 64x64 (optionally fused epilogue) ----
    float* og = uout + (size_t)b * NN * NN;
    if (!FINAL) {
#pragma unroll
        for (int r = 0; r < PT; ++r) {
            int ty = R0 + r - HALO;
#pragma unroll
            for (int c = 0; c < PT; ++c) {
                int tx = C0 + c - HALO;
                if ((unsigned)ty < 64u && (unsigned)tx < 64u)
                    og[(size_t)(oy + ty) * NN + (ox + tx)] = u[r][c];
            }
        }
    } else {
        float w0  = w_back[0], w1 = w_back[1], bb0 = b_back[0];
        float rs  = 0.25f / (1.0f + expf(-logit[0]));
        float ym  = y_mean[0];
        float ysd = y_std[0] + EPS_F;
        const float4* xm4 = (const float4*)x_mix;
#pragma unroll
        for (int r = 0; r < PT; ++r) {
            int ty = R0 + r - HALO;
#pragma unroll
            for (int c = 0; c < PT; ++c) {
                int tx = C0 + c - HALO;
                if ((unsigned)ty < 64u && (unsigned)tx < 64u) {
                    int gi = oy + ty, gj = ox + tx;
                    size_t gidx = (size_t)b * NN * NN + (size_t)gi * NN + gj;
                    float4 xm = xm4[gidx];
                    float e  = (u[r][c] - ym) / ysd;
                    float rr = xm.x * w0 + xm.y * w1 + bb0;
                    float xs = (float)gi * (1.0f / 511.0f);
                    float ys = (float)gj * (1.0f / 511.0f);
                    float dd = fminf(fminf(xs, 1.0f - xs), fminf(ys, 1.0f - ys));
                    float ww = fminf(fmaxf(dd * (1.0f / DELTA_F), 0.0f), 1.0f);
                    if (xm.z > 0.5f) ww = 0.0f;
                    og[(size_t)gi * NN + gj] = e + ww * rs * rr;
                }
            }
        }
    }
}

// ---------------------------------------------------------------------------
extern "C" void kernel_launch(void* const* d_in, const int* in_sizes, int n_in,
                              void* d_out, int out_size, void* d_ws, size_t ws_size,
                              hipStream_t stream)
{
    const float* x_mix  = (const float*)d_in[0];
    const float* w_back = (const float*)d_in[1];
    const float* b_back = (const float*)d_in[2];
    const float* logit  = (const float*)d_in[3];
    const float* y_mean = (const float*)d_in[4];
    const float* y_std  = (const float*)d_in[5];

    float* out = (float*)d_out;

    // Workspace: u_a (16 MB floats) | cmask (4 MB bytes)
    float* u_a = (float*)d_ws;
    unsigned char* cmask = (unsigned char*)((char*)d_ws + (size_t)TOTAL * sizeof(float));

    const int block = 256;
    const int grid1d = (TOTAL + block - 1) / block;

    init_kernel<<<grid1d, block, 0, stream>>>(x_mix, u_a, cmask);

    // 50 iters = 6 launches x 8 + 1 launch x 2 (fused epilogue).
    // Chain: a->o, o->a, a->o, o->a, a->o, o->a, then FINAL a->out.
    dim3 sgrid(NN / 64, NN / 64, BB);   // 8 x 8 x 16 = 1024 blocks (4/CU)
    stencil_kernel<8, false><<<sgrid, block, 0, stream>>>(u_a, out, cmask, x_mix,
        w_back, b_back, logit, y_mean, y_std);
    stencil_kernel<8, false><<<sgrid, block, 0, stream>>>(out, u_a, cmask, x_mix,
        w_back, b_back, logit, y_mean, y_std);
    stencil_kernel<8, false><<<sgrid, block, 0, stream>>>(u_a, out, cmask, x_mix,
        w_back, b_back, logit, y_mean, y_std);
    stencil_kernel<8, false><<<sgrid, block, 0, stream>>>(out, u_a, cmask, x_mix,
        w_back, b_back, logit, y_mean, y_std);
    stencil_kernel<8, false><<<sgrid, block, 0, stream>>>(u_a, out, cmask, x_mix,
        w_back, b_back, logit, y_mean, y_std);
    stencil_kernel<8, false><<<sgrid, block, 0, stream>>>(out, u_a, cmask, x_mix,
        w_back, b_back, logit, y_mean, y_std);
    stencil_kernel<2, true><<<sgrid, block, 0, stream>>>(u_a, out, cmask, x_mix,
        w_back, b_back, logit, y_mean, y_std);
}

// Round 7
// 138.491 us; speedup vs baseline: 1.1700x; 1.1236x over previous
//
#include <hip/hip_runtime.h>
#include <math.h>

#define NN 512
#define BB 16
#define TOTAL (BB * NN * NN)   // 4,194,304 cells
#define EPS_F 1e-5f
#define DELTA_F 0.05f

#define HALO 8
#define LR   80                 // 64 + 2*HALO register tile
#define PT   5                  // cells per thread per dim (80/16)

// bf16 helpers (storage only; all math in f32)
__device__ __forceinline__ float bf16_ld(unsigned short h) {
    return __uint_as_float((unsigned)h << 16);
}
__device__ __forceinline__ unsigned short bf16_st(float f) {
    unsigned b = __float_as_uint(f);
    return (unsigned short)((b + 0x7FFFu + ((b >> 16) & 1u)) >> 16);  // RNE
}

// lane gets lane-1 (within each 16-lane DPP row); boundary lanes -> 0
__device__ __forceinline__ float dpp_shr1(float x) {
    int r = __builtin_amdgcn_update_dpp(0, __float_as_int(x), 0x111, 0xf, 0xf, true);
    return __int_as_float(r);
}
// lane gets lane+1; boundary lanes -> 0
__device__ __forceinline__ float dpp_shl1(float x) {
    int r = __builtin_amdgcn_update_dpp(0, __float_as_int(x), 0x101, 0xf, 0xf, true);
    return __int_as_float(r);
}

// ---------------------------------------------------------------------------
// Init: u0(bf16) = dir ? bc : 0 ; cmask(u8) = fluid ;
// pre(bf16) = w_outer(i,j) * [geom<=0.5] * (x·w_back + b_back)
// ---------------------------------------------------------------------------
__global__ __launch_bounds__(256) void init_kernel(
    const float* __restrict__ x_mix,
    unsigned short* __restrict__ u,
    unsigned char* __restrict__ cmask,
    unsigned short* __restrict__ pre,
    const float* __restrict__ w_back,
    const float* __restrict__ b_back)
{
    int idx = blockIdx.x * blockDim.x + threadIdx.x;
    if (idx >= TOTAL) return;
    int j = idx & (NN - 1);
    int i = (idx >> 9) & (NN - 1);
    float4 xm = reinterpret_cast<const float4*>(x_mix)[idx];
    bool edge = (i == 0) | (i == NN - 1) | (j == 0) | (j == NN - 1);
    bool dir  = edge || (xm.z > 0.5f);
    cmask[idx] = dir ? 0 : 1;
    u[idx]     = bf16_st(dir ? xm.w : 0.0f);

    float rr = xm.x * w_back[0] + xm.y * w_back[1] + b_back[0];
    float xs = (float)i * (1.0f / 511.0f);
    float ys = (float)j * (1.0f / 511.0f);
    float dd = fminf(fminf(xs, 1.0f - xs), fminf(ys, 1.0f - ys));
    float ww = fminf(fmaxf(dd * (1.0f / DELTA_F), 0.0f), 1.0f);
    if (xm.z > 0.5f) ww = 0.0f;
    pre[idx] = bf16_st(ww * rr);
}

// ---------------------------------------------------------------------------
// Register-tile temporal-blocked stencil, 5x5 cells/thread, bf16 state I/O.
// 16x16 threads own an 80x80 tile (64x64 output, halo 8 >= ITERS).
// u and fluid coeffs live in VGPRs (f32); vertical halo via transposed
// conflict-free LDS (double-buffered, 1 barrier/iter); horizontal halo via
// DPP lane shifts. Ring cells frozen (cf=0) annihilate garbage halo values.
// ---------------------------------------------------------------------------
template<int ITERS, bool FINAL>
__global__ __launch_bounds__(256, 4) void stencil_kernel(
    const unsigned short* __restrict__ uin,
    unsigned short* __restrict__ uout,      // bf16 dest (non-final)
    float* __restrict__ fout,               // f32 dest (final)
    const unsigned char* __restrict__ cmask,
    const unsigned short* __restrict__ pre,
    const float* __restrict__ logit,
    const float* __restrict__ y_mean,
    const float* __restrict__ y_std)
{
    __shared__ float xup[2][PT][256];   // thread's row 0 (consumed by tr-1)
    __shared__ float xdn[2][PT][256];   // thread's row PT-1 (consumed by tr+1)

    const int b   = blockIdx.z;
    const int oy  = blockIdx.y * 64;
    const int ox  = blockIdx.x * 64;
    const int tid = threadIdx.x;
    const int tr  = tid >> 4;
    const int tc  = tid & 15;
    const int R0  = tr * PT;
    const int C0  = tc * PT;

    const unsigned short* ub = uin + (size_t)b * NN * NN;
    const unsigned char*  cb = cmask + (size_t)b * NN * NN;

    float u[PT][PT];
    float cf[PT][PT];   // 1.0 = fluid (update), 0.0 = Dirichlet/frozen

    // ---- setup: load 5x5 u + coeffs (clamped; tile ring frozen) ----
#pragma unroll
    for (int r = 0; r < PT; ++r) {
        int ty = R0 + r;
        int gi = oy - HALO + ty;
        gi = min(max(gi, 0), NN - 1);
#pragma unroll
        for (int c = 0; c < PT; ++c) {
            int tx = C0 + c;
            int gj = ox - HALO + tx;
            gj = min(max(gj, 0), NN - 1);
            u[r][c] = bf16_ld(ub[gi * NN + gj]);
            unsigned m = cb[gi * NN + gj];
            bool ring = (ty == 0) | (ty == LR - 1) | (tx == 0) | (tx == LR - 1);
            cf[r][c] = (ring || m == 0u) ? 0.0f : 1.0f;
        }
    }

    const int tup = (tid >= 16)  ? tid - 16 : tid;   // clamped neighbor indices
    const int tdn = (tid < 240)  ? tid + 16 : tid;

    // ---- ITERS fused Jacobi iterations, all in registers ----
#pragma unroll 1
    for (int t = 0; t < ITERS; ++t) {
        const int pb = t & 1;
        // publish OLD boundary rows (transposed layout: conflict-free b32)
#pragma unroll
        for (int w = 0; w < PT; ++w) {
            xup[pb][w][tid] = u[0][w];
            xdn[pb][w][tid] = u[PT - 1][w];
        }
        // capture OLD horizontal neighbor cols via DPP (pure VALU)
        float lsh[PT], rsh[PT];
#pragma unroll
        for (int r = 0; r < PT; ++r) {
            lsh[r] = dpp_shr1(u[r][PT - 1]);
            rsh[r] = dpp_shl1(u[r][0]);
        }
        __syncthreads();
        float th[PT], bh[PT];
#pragma unroll
        for (int w = 0; w < PT; ++w) {
            th[w] = xdn[pb][w][tup];   // garbage for tr==0: ring cf=0 kills it
            bh[w] = xup[pb][w][tdn];   // garbage for tr==15: ring cf=0 kills it
        }
        // in-register raster update; orow/prow keep OLD values (pure SSA)
        float prow[PT];
#pragma unroll
        for (int c = 0; c < PT; ++c) prow[c] = th[c];
#pragma unroll
        for (int r = 0; r < PT; ++r) {
            float orow[PT];
#pragma unroll
            for (int c = 0; c < PT; ++c) orow[c] = u[r][c];
#pragma unroll
            for (int c = 0; c < PT; ++c) {
                float up = prow[c];
                float dn = (r < PT - 1) ? u[r + 1][c] : bh[c];
                float lf = (c > 0)      ? orow[c - 1] : lsh[r];
                float rt = (c < PT - 1) ? orow[c + 1] : rsh[r];
                float s  = (up + dn) + (lf + rt);
                float od = orow[c];
                float tq = __builtin_fmaf(0.25f, s, -od);
                u[r][c]  = __builtin_fmaf(cf[r][c], tq, od);
            }
#pragma unroll
            for (int c = 0; c < PT; ++c) prow[c] = orow[c];
        }
    }

    // ---- store center 64x64 ----
    if (!FINAL) {
        unsigned short* og = uout + (size_t)b * NN * NN;
#pragma unroll
        for (int r = 0; r < PT; ++r) {
            int ty = R0 + r - HALO;
#pragma unroll
            for (int c = 0; c < PT; ++c) {
                int tx = C0 + c - HALO;
                if ((unsigned)ty < 64u && (unsigned)tx < 64u)
                    og[(size_t)(oy + ty) * NN + (ox + tx)] = bf16_st(u[r][c]);
            }
        }
    } else {
        float* og = fout + (size_t)b * NN * NN;
        const unsigned short* pg = pre + (size_t)b * NN * NN;
        float rs  = 0.25f / (1.0f + expf(-logit[0]));
        float ym  = y_mean[0];
        float inv = 1.0f / (y_std[0] + EPS_F);
#pragma unroll
        for (int r = 0; r < PT; ++r) {
            int ty = R0 + r - HALO;
#pragma unroll
            for (int c = 0; c < PT; ++c) {
                int tx = C0 + c - HALO;
                if ((unsigned)ty < 64u && (unsigned)tx < 64u) {
                    int gi = oy + ty, gj = ox + tx;
                    float e = (u[r][c] - ym) * inv;
                    float p = bf16_ld(pg[(size_t)gi * NN + gj]);
                    og[(size_t)gi * NN + gj] = __builtin_fmaf(rs, p, e);
                }
            }
        }
    }
}

// ---------------------------------------------------------------------------
extern "C" void kernel_launch(void* const* d_in, const int* in_sizes, int n_in,
                              void* d_out, int out_size, void* d_ws, size_t ws_size,
                              hipStream_t stream)
{
    const float* x_mix  = (const float*)d_in[0];
    const float* w_back = (const float*)d_in[1];
    const float* b_back = (const float*)d_in[2];
    const float* logit  = (const float*)d_in[3];
    const float* y_mean = (const float*)d_in[4];
    const float* y_std  = (const float*)d_in[5];

    float* out = (float*)d_out;

    // Workspace: u_a bf16 (8.4 MB) | u_b bf16 (8.4 MB) | cmask u8 (4.2 MB) |
    //            pre bf16 (8.4 MB)
    char* ws = (char*)d_ws;
    unsigned short* u_a   = (unsigned short*)ws;
    unsigned short* u_b   = (unsigned short*)(ws + (size_t)TOTAL * 2);
    unsigned char*  cmask = (unsigned char*) (ws + (size_t)TOTAL * 4);
    unsigned short* pre   = (unsigned short*)(ws + (size_t)TOTAL * 5);

    const int block = 256;
    const int grid1d = (TOTAL + block - 1) / block;

    init_kernel<<<grid1d, block, 0, stream>>>(x_mix, u_a, cmask, pre,
                                              w_back, b_back);

    // 50 iters = 6 launches x 8 + 1 launch x 2 (fused epilogue).
    // Chain: a->b, b->a, a->b, b->a, a->b, b->a, then FINAL a->out.
    dim3 sgrid(NN / 64, NN / 64, BB);   // 8 x 8 x 16 = 1024 blocks (4/CU)
    stencil_kernel<8, false><<<sgrid, block, 0, stream>>>(u_a, u_b, out, cmask,
        pre, logit, y_mean, y_std);
    stencil_kernel<8, false><<<sgrid, block, 0, stream>>>(u_b, u_a, out, cmask,
        pre, logit, y_mean, y_std);
    stencil_kernel<8, false><<<sgrid, block, 0, stream>>>(u_a, u_b, out, cmask,
        pre, logit, y_mean, y_std);
    stencil_kernel<8, false><<<sgrid, block, 0, stream>>>(u_b, u_a, out, cmask,
        pre, logit, y_mean, y_std);
    stencil_kernel<8, false><<<sgrid, block, 0, stream>>>(u_a, u_b, out, cmask,
        pre, logit, y_mean, y_std);
    stencil_kernel<8, false><<<sgrid, block, 0, stream>>>(u_b, u_a, out, cmask,
        pre, logit, y_mean, y_std);
    stencil_kernel<2, true><<<sgrid, block, 0, stream>>>(u_a, u_b, out, cmask,
        pre, logit, y_mean, y_std);
}